// Round 4
// baseline (254.480 us; speedup 1.0000x reference)
//
#include <hip/hip_runtime.h>
#include <hip/hip_bf16.h>

// SelfAttention1d  B=16, C=512, L=1024
// R4: pipelined K-loop — triple-buffered LDS (48 KB), depth-2 prefetch,
//     raw s_barrier + s_waitcnt vmcnt(4) so next-tile global_load_lds stay in
//     flight across the barrier (kills the vmcnt(0) drain stall).
//     All GEMMs restructured so epilogues are packed transposed stores
//     (ushort4 / float4 along m), no scalar-store epilogues anywhere.

#define BB 16
#define CC 512
#define LL 1024

typedef __bf16 bf16x8 __attribute__((ext_vector_type(8)));
typedef float  f32x4  __attribute__((ext_vector_type(4)));

__device__ inline unsigned short bf16_bits(float f) {
  __hip_bfloat16 h = __float2bfloat16(f);
  return __builtin_bit_cast(unsigned short, h);
}
__device__ inline float bits_lo(unsigned int u) {
  return __builtin_bit_cast(float, u << 16);
}
__device__ inline float bits_hi(unsigned int u) {
  return __builtin_bit_cast(float, u & 0xffff0000u);
}

// ---------------- BN stats: one block per channel ----------------
__global__ __launch_bounds__(256) void bn_stats(
    const float* __restrict__ x, const float* __restrict__ gamma,
    const float* __restrict__ beta, float* __restrict__ scl,
    float* __restrict__ sft) {
  int c = blockIdx.x;
  int t = threadIdx.x;
  float s = 0.f, s2 = 0.f;
  for (int b = 0; b < BB; ++b) {
    float4 v = ((const float4*)(x + ((size_t)(b * CC + c)) * LL))[t];
    s  += v.x + v.y + v.z + v.w;
    s2 += v.x * v.x + v.y * v.y + v.z * v.z + v.w * v.w;
  }
  for (int m = 32; m; m >>= 1) { s += __shfl_xor(s, m, 64); s2 += __shfl_xor(s2, m, 64); }
  __shared__ float rs[4], rs2[4];
  int wave = t >> 6, lane = t & 63;
  if (lane == 0) { rs[wave] = s; rs2[wave] = s2; }
  __syncthreads();
  if (t == 0) {
    float S  = rs[0] + rs[1] + rs[2] + rs[3];
    float S2 = rs2[0] + rs2[1] + rs2[2] + rs2[3];
    float mean = S * (1.f / 16384.f);
    float var  = S2 * (1.f / 16384.f) - mean * mean;
    float sc = gamma[c] * rsqrtf(var + 1e-5f);
    scl[c] = sc;
    sft[c] = beta[c] - mean * sc;
  }
}

// ---------------- weight casts ----------------
__global__ __launch_bounds__(256) void cast4(
    const float* __restrict__ Wq, const float* __restrict__ Wk,
    const float* __restrict__ Wv, const float* __restrict__ Wp,
    __hip_bfloat16* __restrict__ Wqk, __hip_bfloat16* __restrict__ Wvb,
    __hip_bfloat16* __restrict__ Wpb) {
  int m = blockIdx.y;
  const float* src = m == 0 ? Wq : m == 1 ? Wk : m == 2 ? Wv : Wp;
  __hip_bfloat16* dst = m == 0 ? Wqk : m == 1 ? Wqk + 262144 : m == 2 ? Wvb : Wpb;
  int i = blockIdx.x * 256 + threadIdx.x;
  float4 v = ((const float4*)src)[i];
  ushort4 o;
  o.x = bf16_bits(v.x); o.y = bf16_bits(v.y);
  o.z = bf16_bits(v.z); o.w = bf16_bits(v.w);
  ((ushort4*)dst)[i] = o;
}

// ---------------- normalize + transpose: x [B][C][L] -> hnT [B][L][C] bf16 ----
__global__ __launch_bounds__(256) void norm_t(
    const float* __restrict__ x, const float* __restrict__ scl,
    const float* __restrict__ sft, __hip_bfloat16* __restrict__ hnT) {
  __shared__ float tile[32][33];
  int l0 = blockIdx.x * 32, c0 = blockIdx.y * 32, b = blockIdx.z;
  int t = threadIdx.x;
#pragma unroll
  for (int i = 0; i < 4; ++i) {
    int idx = t + i * 256;
    int cc = idx >> 5, ll = idx & 31;
    tile[cc][ll] = x[((size_t)(b * CC + c0 + cc)) * LL + l0 + ll];
  }
  __syncthreads();
#pragma unroll
  for (int i = 0; i < 2; ++i) {
    int idx = t + i * 256;
    int ll = idx >> 4, cc = (idx & 15) * 2;
    float v0 = tile[cc][ll] * scl[c0 + cc] + sft[c0 + cc];
    float v1 = tile[cc + 1][ll] * scl[c0 + cc + 1] + sft[c0 + cc + 1];
    ushort2 o; o.x = bf16_bits(v0); o.y = bf16_bits(v1);
    *(ushort2*)(hnT + ((size_t)(b * LL + l0 + ll)) * CC + c0 + cc) = o;
  }
}

// ---------------- softmax: one row per wave, bf16 in place ----------------
__global__ __launch_bounds__(256) void softmax_bf16(__hip_bfloat16* __restrict__ S) {
  int wave = threadIdx.x >> 6, lane = threadIdx.x & 63;
  size_t row = (size_t)blockIdx.x * 4 + wave;
  uint4* p = (uint4*)(S + row * 1024);
  uint4 r0 = p[lane * 2], r1 = p[lane * 2 + 1];
  float f[16];
  unsigned int w[8] = {r0.x, r0.y, r0.z, r0.w, r1.x, r1.y, r1.z, r1.w};
#pragma unroll
  for (int i = 0; i < 8; ++i) { f[2 * i] = bits_lo(w[i]); f[2 * i + 1] = bits_hi(w[i]); }
  float mx = f[0];
#pragma unroll
  for (int i = 1; i < 16; ++i) mx = fmaxf(mx, f[i]);
  for (int m = 32; m; m >>= 1) mx = fmaxf(mx, __shfl_xor(mx, m, 64));
  float s = 0.f;
#pragma unroll
  for (int i = 0; i < 16; ++i) { f[i] = __expf(f[i] - mx); s += f[i]; }
  for (int m = 32; m; m >>= 1) s += __shfl_xor(s, m, 64);
  float inv = 1.f / s;
  unsigned int ow[8];
#pragma unroll
  for (int i = 0; i < 8; ++i) {
    unsigned int lo = bf16_bits(f[2 * i] * inv);
    unsigned int hi = bf16_bits(f[2 * i + 1] * inv);
    ow[i] = lo | (hi << 16);
  }
  uint4 o0 = {ow[0], ow[1], ow[2], ow[3]}, o1 = {ow[4], ow[5], ow[6], ow[7]};
  p[lane * 2] = o0; p[lane * 2 + 1] = o1;
}

// ---------------- pipelined GEMM core ----------------
// acc[m-sub][n-sub] += A[128xK] * B[128xK]^T, both [row][k] k-contiguous.
// Triple-buffered LDS (sm = 3 bufs x (4096 A + 4096 B) bf16), depth-2
// prefetch via global_load_lds; one s_barrier per iter, s_waitcnt vmcnt(4)
// keeps next tile's 4 loads in flight across the barrier.
__device__ inline void glds(const __hip_bfloat16* g, __hip_bfloat16* l) {
  __builtin_amdgcn_global_load_lds(
      (__attribute__((address_space(1))) void*)(void*)g,
      (__attribute__((address_space(3))) void*)l, 16, 0, 0);
}

__device__ __forceinline__ void gemm_core(
    const __hip_bfloat16* __restrict__ A, int lda,
    const __hip_bfloat16* __restrict__ B, int ldb, int K,
    __hip_bfloat16* sm, f32x4 (&acc)[4][4]) {
  const int tid = threadIdx.x;
  const int wave = tid >> 6, lane = tid & 63;
  const int wm = (wave >> 1) * 64, wn = (wave & 1) * 64;
  const int row0 = tid >> 2;                             // 0..63
  const int ke0 = (((tid & 3) ^ ((tid >> 3) & 3)) * 8);  // swizzled fetch chunk
  const int fr = lane & 15;
  const int q = lane >> 4;
  const int colA = ((q ^ ((fr >> 1) & 3)) * 8);          // swizzled read col
  const int dofs = wave * 512;                           // LDS elem offset, it=0

  const __hip_bfloat16* ga0 = A + (size_t)row0 * lda + ke0;
  const __hip_bfloat16* ga1 = ga0 + (size_t)64 * lda;
  const __hip_bfloat16* gb0 = B + (size_t)row0 * ldb + ke0;
  const __hip_bfloat16* gb1 = gb0 + (size_t)64 * ldb;

  __hip_bfloat16* rb = sm;            // read buf (tile k)
  __hip_bfloat16* nb = sm + 8192;     // tile k+1 (in flight)
  __hip_bfloat16* wb = sm + 16384;    // stage target for tile k+2

  const int niters = K >> 5;
  // prologue: stage tiles 0,1
  {
    glds(ga0, rb + dofs);          glds(ga1, rb + 2048 + dofs);
    glds(gb0, rb + 4096 + dofs);   glds(gb1, rb + 6144 + dofs);
    glds(ga0 + 32, nb + dofs);        glds(ga1 + 32, nb + 2048 + dofs);
    glds(gb0 + 32, nb + 4096 + dofs); glds(gb1 + 32, nb + 6144 + dofs);
  }
  for (int k = 0; k < niters; ++k) {
    if (k + 1 < niters) __builtin_amdgcn_s_waitcnt(0x0F74);  // vmcnt(4)
    else                __builtin_amdgcn_s_waitcnt(0x0F70);  // vmcnt(0)
    __builtin_amdgcn_s_barrier();
    if (k + 2 < niters) {
      int ko = (k + 2) * 32;
      glds(ga0 + ko, wb + dofs);          glds(ga1 + ko, wb + 2048 + dofs);
      glds(gb0 + ko, wb + 4096 + dofs);   glds(gb1 + ko, wb + 6144 + dofs);
    }
    bf16x8 af[4], bfr[4];
#pragma unroll
    for (int i = 0; i < 4; ++i) {
      af[i]  = *(const bf16x8*)(rb + (wm + i * 16 + fr) * 32 + colA);
      bfr[i] = *(const bf16x8*)(rb + 4096 + (wn + i * 16 + fr) * 32 + colA);
    }
#pragma unroll
    for (int i = 0; i < 4; ++i)
#pragma unroll
      for (int j = 0; j < 4; ++j)
        acc[i][j] = __builtin_amdgcn_mfma_f32_16x16x32_bf16(af[i], bfr[j], acc[i][j], 0, 0, 0);
    __hip_bfloat16* t = rb; rb = nb; nb = wb; wb = t;
  }
}

// ---------------- qk GEMM: A=Wq|Wk [1024x512], B=hnT; packed T-store, bias-m --
__global__ __launch_bounds__(256, 3) void gemm_qk(
    const __hip_bfloat16* __restrict__ Wb, const __hip_bfloat16* __restrict__ hnT,
    __hip_bfloat16* __restrict__ qT, __hip_bfloat16* __restrict__ kT,
    const float* __restrict__ bq, const float* __restrict__ bk) {
  __shared__ __align__(16) __hip_bfloat16 sm[3 * 8192];
  const int bat = blockIdx.z;
  const int m0 = blockIdx.y * 128, n0 = blockIdx.x * 128;
  f32x4 acc[4][4] = {};
  gemm_core(Wb + (size_t)m0 * 512, 512,
            hnT + (size_t)bat * LL * CC + (size_t)n0 * 512, 512, 512, sm, acc);
  const int lane = threadIdx.x & 63, wave = threadIdx.x >> 6;
  const int wm = (wave >> 1) * 64, wn = (wave & 1) * 64;
  const int crow = (lane >> 4) * 4, ccol = lane & 15;
  const int id = m0 >> 9;
  const int mloc0 = m0 & 511;
  const float* bias = id == 0 ? bq : bk;
  __hip_bfloat16* D = (id == 0 ? qT : kT) + (size_t)bat * LL * CC;
#pragma unroll
  for (int i = 0; i < 4; ++i) {
    int mg = mloc0 + wm + i * 16 + crow;
    float bv4[4];
#pragma unroll
    for (int r = 0; r < 4; ++r) bv4[r] = bias[mg + r];
#pragma unroll
    for (int j = 0; j < 4; ++j) {
      int ng = n0 + wn + j * 16 + ccol;
      ushort4 o;
      o.x = bf16_bits(acc[i][j][0] + bv4[0]);
      o.y = bf16_bits(acc[i][j][1] + bv4[1]);
      o.z = bf16_bits(acc[i][j][2] + bv4[2]);
      o.w = bf16_bits(acc[i][j][3] + bv4[3]);
      *(ushort4*)(D + (size_t)ng * 512 + mg) = o;
    }
  }
}

// ---------------- generic GEMM, bf16 packed T-store: D[n][m] (+bias[n]) -------
template <bool BIAS>
__global__ __launch_bounds__(256, 3) void gemm_bf16t(
    const __hip_bfloat16* __restrict__ A, int lda, size_t strideA,
    const __hip_bfloat16* __restrict__ B, int ldb, size_t strideB,
    __hip_bfloat16* __restrict__ D, int ldd, size_t strideD,
    const float* __restrict__ bias, float scale, int K) {
  __shared__ __align__(16) __hip_bfloat16 sm[3 * 8192];
  const int bat = blockIdx.z;
  const int m0 = blockIdx.y * 128, n0 = blockIdx.x * 128;
  f32x4 acc[4][4] = {};
  gemm_core(A + (size_t)bat * strideA + (size_t)m0 * lda, lda,
            B + (size_t)bat * strideB + (size_t)n0 * ldb, ldb, K, sm, acc);
  const int lane = threadIdx.x & 63, wave = threadIdx.x >> 6;
  const int wm = (wave >> 1) * 64, wn = (wave & 1) * 64;
  const int crow = (lane >> 4) * 4, ccol = lane & 15;
  __hip_bfloat16* Db = D + (size_t)bat * strideD;
#pragma unroll
  for (int j = 0; j < 4; ++j) {
    int ng = n0 + wn + j * 16 + ccol;
    float bn = BIAS ? bias[ng] : 0.f;
#pragma unroll
    for (int i = 0; i < 4; ++i) {
      int mg = m0 + wm + i * 16 + crow;
      ushort4 o;
      o.x = bf16_bits(acc[i][j][0] * scale + bn);
      o.y = bf16_bits(acc[i][j][1] * scale + bn);
      o.z = bf16_bits(acc[i][j][2] * scale + bn);
      o.w = bf16_bits(acc[i][j][3] * scale + bn);
      *(ushort4*)(Db + (size_t)ng * ldd + mg) = o;
    }
  }
}

// ---------------- proj GEMM, fp32 T-store: D[n][m] = acc + bias[n] + resid ----
__global__ __launch_bounds__(256, 3) void gemm_f32t(
    const __hip_bfloat16* __restrict__ A, int lda, size_t strideA,
    const __hip_bfloat16* __restrict__ B, int ldb,
    float* __restrict__ D, int ldd, size_t strideD,
    const float* __restrict__ bias, const float* __restrict__ resid, int K) {
  __shared__ __align__(16) __hip_bfloat16 sm[3 * 8192];
  const int bat = blockIdx.z;
  const int m0 = blockIdx.y * 128, n0 = blockIdx.x * 128;
  f32x4 acc[4][4] = {};
  gemm_core(A + (size_t)bat * strideA + (size_t)m0 * lda, lda,
            B + (size_t)n0 * ldb, ldb, K, sm, acc);
  const int lane = threadIdx.x & 63, wave = threadIdx.x >> 6;
  const int wm = (wave >> 1) * 64, wn = (wave & 1) * 64;
  const int crow = (lane >> 4) * 4, ccol = lane & 15;
  float* Db = D + (size_t)bat * strideD;
  const float* Rb = resid + (size_t)bat * strideD;
#pragma unroll
  for (int j = 0; j < 4; ++j) {
    int ng = n0 + wn + j * 16 + ccol;
    float bn = bias[ng];
#pragma unroll
    for (int i = 0; i < 4; ++i) {
      int mg = m0 + wm + i * 16 + crow;
      float4 r = *(const float4*)(Rb + (size_t)ng * ldd + mg);
      float4 o;
      o.x = acc[i][j][0] + bn + r.x;
      o.y = acc[i][j][1] + bn + r.y;
      o.z = acc[i][j][2] + bn + r.z;
      o.w = acc[i][j][3] + bn + r.w;
      *(float4*)(Db + (size_t)ng * ldd + mg) = o;
    }
  }
}

extern "C" void kernel_launch(void* const* d_in, const int* in_sizes, int n_in,
                              void* d_out, int out_size, void* d_ws, size_t ws_size,
                              hipStream_t stream) {
  const float* x     = (const float*)d_in[0];
  const float* gamma = (const float*)d_in[1];
  const float* beta  = (const float*)d_in[2];
  const float* Wq    = (const float*)d_in[3];
  const float* bq    = (const float*)d_in[4];
  const float* Wk    = (const float*)d_in[5];
  const float* bk    = (const float*)d_in[6];
  const float* Wv    = (const float*)d_in[7];
  const float* bv    = (const float*)d_in[8];
  const float* Wp    = (const float*)d_in[9];
  const float* bp    = (const float*)d_in[10];
  float* out = (float*)d_out;

  char* ws = (char*)d_ws;
  float* scl = (float*)ws;
  float* sft = scl + 512;
  __hip_bfloat16* Wqkb = (__hip_bfloat16*)(ws + 4096);    // 1024x512
  __hip_bfloat16* Wvb  = Wqkb + 524288;                   // 512x512
  __hip_bfloat16* Wpb  = Wvb + 262144;                    // 512x512
  __hip_bfloat16* hnT  = Wpb + 262144;                    // [B][L][C]
  __hip_bfloat16* qT   = hnT + 8388608;                   // [B][L][C]
  __hip_bfloat16* kT   = qT + 8388608;                    // [B][L][C]
  __hip_bfloat16* vN   = kT + 8388608;                    // [B][C][L]
  __hip_bfloat16* Sb   = vN + 8388608;                    // [B][L][L] bf16
  __hip_bfloat16* HT   = hnT;                             // reuse after v-gemm

  const size_t sLC = (size_t)LL * CC;
  const size_t sCL = (size_t)CC * LL;
  const size_t sLLb = (size_t)LL * LL;

  bn_stats<<<512, 256, 0, stream>>>(x, gamma, beta, scl, sft);
  cast4<<<dim3(256, 4), 256, 0, stream>>>(Wq, Wk, Wv, Wp, Wqkb, Wvb, Wpb);
  norm_t<<<dim3(32, 16, 16), 256, 0, stream>>>(x, scl, sft, hnT);

  // qT,kT = (Wq|Wk · hn)^T  [L][C] packed
  gemm_qk<<<dim3(8, 8, 16), 256, 0, stream>>>(Wqkb, hnT, qT, kT, bq, bk);
  // v [C][L]: A=hnT (m=l), B=Wv (n=c), T-store D[c][l], bias bv[c]
  gemm_bf16t<true><<<dim3(4, 8, 16), 256, 0, stream>>>(
      hnT, 512, sLC, Wvb, 512, 0, vN, 1024, sCL, bv, 1.f, 512);
  // S [i][j]: A=kT (m=j), B=qT (n=i), T-store D[i][j], *C^-0.5
  gemm_bf16t<false><<<dim3(8, 8, 16), 256, 0, stream>>>(
      kT, 512, sLC, qT, 512, sLC, Sb, 1024, sLLb, nullptr,
      0.04419417382415922f, 512);
  softmax_bf16<<<4096, 256, 0, stream>>>(Sb);
  // HT [i][c]: A=vN (m=c), B=Sb (n=i), T-store D[i][c], K=1024
  gemm_bf16t<false><<<dim3(8, 4, 16), 256, 0, stream>>>(
      vN, 1024, sCL, Sb, 1024, sLLb, HT, 512, sLC, nullptr, 1.f, 1024);
  // out [c][i]: A=HT (m=i), B=Wp (n=c_out), fp32 T-store + bp + x
  gemm_f32t<<<dim3(4, 8, 16), 256, 0, stream>>>(
      HT, 512, sLC, Wpb, 512, out, 1024, sCL, bp, x, 512);
}